// Round 1
// baseline (823.796 us; speedup 1.0000x reference)
//
#include <hip/hip_runtime.h>

// AutoEncoder fused pipeline, bf16 MFMA (gfx950).
// Layers: 784->512->264->128->264->512->784, LN+mish between, sigmoid out,
// plus sum(|x_latent|) as second output.

typedef short bf16x8 __attribute__((ext_vector_type(8)));
typedef float f32x4  __attribute__((ext_vector_type(4)));

#define B_ROWS 65536
#define EPS_LN 1e-5f

static __device__ __forceinline__ unsigned short f2bf(float f) {
    union { float f; unsigned u; } v; v.f = f;
    unsigned r = v.u + 0x7FFFu + ((v.u >> 16) & 1u);   // RNE
    return (unsigned short)(r >> 16);
}

static __device__ __forceinline__ float mish_f(float x) {
    // mish(x) = x * tanh(softplus(x)) = x * p/(p+2), p = e^x*(e^x+2)
    if (x > 15.f) return x;
    float u = __expf(x);
    float p = __fmaf_rn(u, u, 2.f * u);
    return x * (p / (p + 2.f));
}

// ---------------- weight fp32->bf16 conversion (one launch) ----------------
struct CvtArgs {
    const float* src[6];
    unsigned short* dst[6];
};

__global__ void wcvt_kernel(CvtArgs a) {
    int b = blockIdx.x;
    int seg, base;
    if      (b <  392) { seg = 0; base = 0;   }
    else if (b <  524) { seg = 1; base = 392; }
    else if (b <  557) { seg = 2; base = 524; }
    else if (b <  590) { seg = 3; base = 557; }
    else if (b <  722) { seg = 4; base = 590; }
    else               { seg = 5; base = 722; }
    int idx = (b - base) * 1024 + threadIdx.x * 4;
    float4 v = *(const float4*)(a.src[seg] + idx);
    ushort4 o;
    o.x = f2bf(v.x); o.y = f2bf(v.y); o.z = f2bf(v.z); o.w = f2bf(v.w);
    *(ushort4*)(a.dst[seg] + idx) = o;
}

// ---------------- fused GEMM + (bias) + LayerNorm + mish ----------------
// C[64 x O] = A[64 x K] @ W[O x K]^T  (+bias), then LN over O, mish, bf16 out.
// Block: 256 threads = 4 waves; wave w owns rows w*16..w*16+15, all O cols.
template<int K, int O, int OP, int NK, bool SRCF32, bool HASBIAS, bool ABS>
__global__ __launch_bounds__(256)
void layer_ln(const void* __restrict__ Asrc,
              const unsigned short* __restrict__ Wb,   // [O][K] bf16
              const float* __restrict__ gam,
              const float* __restrict__ bet,
              const float* __restrict__ bias,          // [O] or null
              unsigned short* __restrict__ Aout,       // [B][O] bf16
              float* __restrict__ partials)
{
    constexpr int NT = OP / 16;
    __shared__ unsigned short Wl[OP * 40];   // +8 pad per 32-col row
    __shared__ unsigned short Al[64 * 40];
    __shared__ float wsum[4];

    const int tid  = threadIdx.x;
    const int row0 = blockIdx.x * 64;
    const int wave = tid >> 6;
    const int lane = tid & 63;
    const int lg   = lane >> 4;        // 0..3
    const int lc   = lane & 15;        // 0..15
    const int kgrp = lg * 8;

    f32x4 acc[NT];
#pragma unroll
    for (int i = 0; i < NT; ++i) acc[i] = (f32x4){0.f, 0.f, 0.f, 0.f};

    const int sr = tid >> 2;           // staging row 0..63
    const int sc = (tid & 3) * 8;      // staging col chunk 0/8/16/24

    for (int ks = 0; ks < NK; ++ks) {
        const int gk = ks * 32 + sc;
        // ---- stage A tile (64 x 32), zero-pad K tail ----
        {
            union { unsigned short us[8]; uint4 v; } t;
            t.v = make_uint4(0u, 0u, 0u, 0u);
            if (gk < K) {
                if constexpr (SRCF32) {
                    const float* ap = (const float*)Asrc + (size_t)(row0 + sr) * K + gk;
                    float4 v0 = *(const float4*)ap;
                    float4 v1 = *(const float4*)(ap + 4);
                    t.us[0] = f2bf(v0.x); t.us[1] = f2bf(v0.y);
                    t.us[2] = f2bf(v0.z); t.us[3] = f2bf(v0.w);
                    t.us[4] = f2bf(v1.x); t.us[5] = f2bf(v1.y);
                    t.us[6] = f2bf(v1.z); t.us[7] = f2bf(v1.w);
                } else {
                    t.v = *(const uint4*)((const unsigned short*)Asrc +
                                          (size_t)(row0 + sr) * K + gk);
                }
            }
            *(uint4*)&Al[sr * 40 + sc] = t.v;
        }
        // ---- stage W tile (OP x 32), zero-pad O and K tails ----
#pragma unroll
        for (int rr = 0; rr < OP; rr += 64) {
            int r = rr + sr;
            uint4 val = make_uint4(0u, 0u, 0u, 0u);
            if (r < O && gk < K)
                val = *(const uint4*)(Wb + (size_t)r * K + gk);
            if (r < OP)
                *(uint4*)&Wl[r * 40 + sc] = val;
        }
        __syncthreads();
        // ---- MFMA ----
        bf16x8 afr = *(const bf16x8*)&Al[(wave * 16 + lc) * 40 + kgrp];
#pragma unroll
        for (int nt = 0; nt < NT; ++nt) {
            bf16x8 bfr = *(const bf16x8*)&Wl[(nt * 16 + lc) * 40 + kgrp];
            acc[nt] = __builtin_amdgcn_mfma_f32_16x16x32_bf16(afr, bfr, acc[nt], 0, 0, 0);
        }
        __syncthreads();
    }

    // ---- epilogue: optional bias, LN stats in-register, mish, store ----
    if constexpr (HASBIAS) {
#pragma unroll
        for (int nt = 0; nt < NT; ++nt) {
            int col = nt * 16 + lc;
            float bv = (col < O) ? bias[col] : 0.f;
#pragma unroll
            for (int r = 0; r < 4; ++r) acc[nt][r] += bv;
        }
    }

    float s1[4] = {0.f, 0.f, 0.f, 0.f}, s2[4] = {0.f, 0.f, 0.f, 0.f};
#pragma unroll
    for (int nt = 0; nt < NT; ++nt) {
        int col = nt * 16 + lc;
        if (col < O) {
#pragma unroll
            for (int r = 0; r < 4; ++r) {
                float v = acc[nt][r];
                s1[r] += v;
                s2[r] = __fmaf_rn(v, v, s2[r]);
            }
        }
    }
#pragma unroll
    for (int m = 1; m < 16; m <<= 1) {
#pragma unroll
        for (int r = 0; r < 4; ++r) {
            s1[r] += __shfl_xor(s1[r], m);
            s2[r] += __shfl_xor(s2[r], m);
        }
    }
    float mu[4], rs[4];
#pragma unroll
    for (int r = 0; r < 4; ++r) {
        mu[r] = s1[r] * (1.f / O);
        float var = fmaxf(s2[r] * (1.f / O) - mu[r] * mu[r], 0.f);
        rs[r] = rsqrtf(var + EPS_LN);
    }

    float asum = 0.f;
#pragma unroll
    for (int nt = 0; nt < NT; ++nt) {
        int col = nt * 16 + lc;
        if (col < O) {
            float gv = gam[col], bv = bet[col];
#pragma unroll
            for (int r = 0; r < 4; ++r) {
                float v = (acc[nt][r] - mu[r]) * rs[r] * gv + bv;
                float mz = mish_f(v);
                if (ABS) asum += fabsf(mz);
                int row = row0 + wave * 16 + lg * 4 + r;
                Aout[(size_t)row * O + col] = f2bf(mz);
            }
        }
    }

    if constexpr (ABS) {
#pragma unroll
        for (int m = 1; m < 64; m <<= 1) asum += __shfl_xor(asum, m);
        if (lane == 0) wsum[wave] = asum;
        __syncthreads();
        if (tid == 0)
            partials[blockIdx.x] = (wsum[0] + wsum[1]) + (wsum[2] + wsum[3]);
    }
}

// ---------------- final layer: GEMM + bias + sigmoid, fp32 out ----------------
// grid (B/64, 7): block computes 64 rows x 112 cols of the 784-wide output.
template<int K, int NK>
__global__ __launch_bounds__(256)
void layer_out(const unsigned short* __restrict__ Asrc, // [B][512] bf16
               const unsigned short* __restrict__ Wb,   // [784][512] bf16
               const float* __restrict__ bias,          // [784]
               float* __restrict__ Out)                 // [B][784] fp32
{
    constexpr int CT = 112, NT = 7, OFULL = 784;
    __shared__ unsigned short Wl[CT * 40];
    __shared__ unsigned short Al[64 * 40];

    const int tid  = threadIdx.x;
    const int row0 = blockIdx.x * 64;
    const int c0   = blockIdx.y * CT;
    const int wave = tid >> 6;
    const int lane = tid & 63;
    const int lg   = lane >> 4;
    const int lc   = lane & 15;
    const int kgrp = lg * 8;

    f32x4 acc[NT];
#pragma unroll
    for (int i = 0; i < NT; ++i) acc[i] = (f32x4){0.f, 0.f, 0.f, 0.f};

    const int sr = tid >> 2;
    const int sc = (tid & 3) * 8;

    for (int ks = 0; ks < NK; ++ks) {
        const int gk = ks * 32 + sc;
        {
            uint4 t = make_uint4(0u, 0u, 0u, 0u);
            if (gk < K)
                t = *(const uint4*)(Asrc + (size_t)(row0 + sr) * K + gk);
            *(uint4*)&Al[sr * 40 + sc] = t;
        }
#pragma unroll
        for (int rr = 0; rr < CT; rr += 64) {
            int r = rr + sr;
            if (r < CT) {
                uint4 val = make_uint4(0u, 0u, 0u, 0u);
                if (gk < K)
                    val = *(const uint4*)(Wb + (size_t)(c0 + r) * K + gk);
                *(uint4*)&Wl[r * 40 + sc] = val;
            }
        }
        __syncthreads();
        bf16x8 afr = *(const bf16x8*)&Al[(wave * 16 + lc) * 40 + kgrp];
#pragma unroll
        for (int nt = 0; nt < NT; ++nt) {
            bf16x8 bfr = *(const bf16x8*)&Wl[(nt * 16 + lc) * 40 + kgrp];
            acc[nt] = __builtin_amdgcn_mfma_f32_16x16x32_bf16(afr, bfr, acc[nt], 0, 0, 0);
        }
        __syncthreads();
    }

#pragma unroll
    for (int nt = 0; nt < NT; ++nt) {
        int col = c0 + nt * 16 + lc;
        float bv = bias[col];
#pragma unroll
        for (int r = 0; r < 4; ++r) {
            float v = acc[nt][r] + bv;
            float s = 1.f / (1.f + __expf(-v));
            int row = row0 + wave * 16 + lg * 4 + r;
            Out[(size_t)row * OFULL + col] = s;
        }
    }
}

// ---------------- deterministic final reduction of |latent| partials ----------------
__global__ void reduce_abs(const float* __restrict__ partials, float* __restrict__ out) {
    __shared__ float sm[256];
    float s = 0.f;
    for (int i = threadIdx.x; i < 1024; i += 256) s += partials[i];  // fixed order
    sm[threadIdx.x] = s;
    __syncthreads();
    for (int step = 128; step > 0; step >>= 1) {
        if (threadIdx.x < step) sm[threadIdx.x] += sm[threadIdx.x + step];
        __syncthreads();
    }
    if (threadIdx.x == 0) out[0] = sm[0];
}

extern "C" void kernel_launch(void* const* d_in, const int* in_sizes, int n_in,
                              void* d_out, int out_size, void* d_ws, size_t ws_size,
                              hipStream_t stream)
{
    const float* x   = (const float*)d_in[0];
    const float* W1  = (const float*)d_in[1];
    const float* g1  = (const float*)d_in[2];
    const float* b1  = (const float*)d_in[3];
    const float* W2  = (const float*)d_in[4];
    const float* g2  = (const float*)d_in[5];
    const float* b2  = (const float*)d_in[6];
    const float* W3  = (const float*)d_in[7];
    const float* b3  = (const float*)d_in[8];
    const float* gh  = (const float*)d_in[9];
    const float* bh  = (const float*)d_in[10];
    const float* D1  = (const float*)d_in[11];
    const float* g3  = (const float*)d_in[12];
    const float* b3n = (const float*)d_in[13];
    const float* D2  = (const float*)d_in[14];
    const float* g4  = (const float*)d_in[15];
    const float* b4  = (const float*)d_in[16];
    const float* D3  = (const float*)d_in[17];
    const float* bo  = (const float*)d_in[18];

    char* ws = (char*)d_ws;
    size_t off = 0;
    auto alloc = [&](size_t bytes) -> char* {
        char* p = ws + off;
        off += (bytes + 255) & ~(size_t)255;
        return p;
    };
    unsigned short* W1b = (unsigned short*)alloc((size_t)512 * 784 * 2);
    unsigned short* W2b = (unsigned short*)alloc((size_t)264 * 512 * 2);
    unsigned short* W3b = (unsigned short*)alloc((size_t)128 * 264 * 2);
    unsigned short* D1b = (unsigned short*)alloc((size_t)264 * 128 * 2);
    unsigned short* D2b = (unsigned short*)alloc((size_t)512 * 264 * 2);
    unsigned short* D3b = (unsigned short*)alloc((size_t)784 * 512 * 2);
    unsigned short* actP = (unsigned short*)alloc((size_t)B_ROWS * 512 * 2);
    unsigned short* actQ = (unsigned short*)alloc((size_t)B_ROWS * 264 * 2);
    float* partials = (float*)alloc(1024 * 4);

    CvtArgs ca;
    ca.src[0] = W1; ca.dst[0] = W1b;
    ca.src[1] = W2; ca.dst[1] = W2b;
    ca.src[2] = W3; ca.dst[2] = W3b;
    ca.src[3] = D1; ca.dst[3] = D1b;
    ca.src[4] = D2; ca.dst[4] = D2b;
    ca.src[5] = D3; ca.dst[5] = D3b;
    wcvt_kernel<<<1114, 256, 0, stream>>>(ca);

    const int NB = B_ROWS / 64;  // 1024

    // L1: x[.,784] @ W1^T -> 512, LN(g1,b1), mish
    layer_ln<784, 512, 512, 25, true,  false, false>
        <<<NB, 256, 0, stream>>>(x, W1b, g1, b1, nullptr, actP, nullptr);
    // L2: -> 264, LN(g2,b2), mish
    layer_ln<512, 264, 272, 16, false, false, false>
        <<<NB, 256, 0, stream>>>(actP, W2b, g2, b2, nullptr, actQ, nullptr);
    // L3: -> 128 (+b3 before LN), LN(gh,bh), mish, abs-partials
    layer_ln<264, 128, 128, 9,  false, true,  true>
        <<<NB, 256, 0, stream>>>(actQ, W3b, gh, bh, b3, actP, partials);
    // L4: -> 264, LN(g3,b3n), mish
    layer_ln<128, 264, 272, 4,  false, false, false>
        <<<NB, 256, 0, stream>>>(actP, D1b, g3, b3n, nullptr, actQ, nullptr);
    // L5: -> 512, LN(g4,b4), mish
    layer_ln<264, 512, 512, 9,  false, false, false>
        <<<NB, 256, 0, stream>>>(actQ, D2b, g4, b4, nullptr, actP, nullptr);
    // L6: -> 784, +bo, sigmoid, fp32 out
    dim3 g6(NB, 7);
    layer_out<512, 16><<<g6, 256, 0, stream>>>(actP, D3b, bo, (float*)d_out);

    reduce_abs<<<1, 256, 0, stream>>>(partials, (float*)d_out + (size_t)B_ROWS * 784);
}

// Round 2
// 590.627 us; speedup vs baseline: 1.3948x; 1.3948x over previous
//
#include <hip/hip_runtime.h>

// AutoEncoder fused pipeline v2, bf16 MFMA (gfx950).
// 128-row x full-O blocks, 8 waves (2x4), double-buffered LDS, reg-staged
// 2-phase pipeline. Layers: 784->512->264->128->264->512->784.

typedef short bf16x8 __attribute__((ext_vector_type(8)));
typedef float f32x4  __attribute__((ext_vector_type(4)));

#define B_ROWS 65536
#define EPS_LN 1e-5f

static __device__ __forceinline__ unsigned short f2bf(float f) {
    union { float f; unsigned u; } v; v.f = f;
    unsigned r = v.u + 0x7FFFu + ((v.u >> 16) & 1u);   // RNE
    return (unsigned short)(r >> 16);
}

static __device__ __forceinline__ float mish_f(float x) {
    if (x > 15.f) return x;
    float u = __expf(x);
    float p = __fmaf_rn(u, u, 2.f * u);
    return x * (p / (p + 2.f));
}

// ---------------- padded weight fp32->bf16 conversion ----------------
struct CvtArgs {
    const float* src[6];
    unsigned short* dst[6];
    int O[6], K[6], KP[6];
    int base[7];
};

__global__ void wpad_kernel(CvtArgs a) {
    int b = blockIdx.x;
    int seg = 0;
    while (b >= a.base[seg + 1]) ++seg;
    int r = b - a.base[seg];
    int O = a.O[seg], K = a.K[seg], KP = a.KP[seg];
    const float* s = a.src[seg];
    unsigned short* d = a.dst[seg];
    for (int c = threadIdx.x; c < KP; c += 256) {
        unsigned short v = 0;
        if (r < O && c < K) v = f2bf(s[(size_t)r * K + c]);
        d[(size_t)r * KP + c] = v;
    }
}

// ---------------- fused layer kernel ----------------
// Block: 512 threads = 8 waves arranged 2(row) x 4(col).
// Tile: 128 rows x OP cols.  Wave tile: 64 rows x NT*16 cols.
// KP: padded K (source stride ASTR, real-K guard only for fp32 source).
// Double-buffered LDS, loads issued one iteration ahead.
template<int KP, int ASTR, int OP, int OREAL, int OSTRIDE, int NKT,
         bool SRCF32, bool HASBIAS, bool ABS, bool LN>
__global__ __launch_bounds__(512)
void layer2(const void* __restrict__ Asrc,
            const unsigned short* __restrict__ Wp,
            const float* __restrict__ gam,
            const float* __restrict__ bet,
            const float* __restrict__ bias,
            void* __restrict__ Aout,
            float* __restrict__ partials)
{
    constexpr int NT  = OP / 64;           // col frags per wave
    constexpr int NPB = (OP + 127) / 128;  // B staging passes

    __shared__ unsigned short Al[2][128 * 40];
    __shared__ unsigned short Wl[2][OP * 40];
    __shared__ float lnP[LN ? 1024 : 1];
    __shared__ float lnMR[LN ? 256 : 1];
    __shared__ float wsum[ABS ? 8 : 1];

    const int tid  = threadIdx.x;
    const int wave = tid >> 6, lane = tid & 63;
    const int wr = wave >> 2, wc = wave & 3;
    const int lg = lane >> 4, lc = lane & 15;
    const int row0  = blockIdx.x * 128;
    const int cbase = blockIdx.y * OP;   // 0 for LN layers

    const int sr  = tid >> 2;            // staging row 0..127
    const int sc8 = (tid & 3) * 8;       // staging col chunk

    const unsigned short* abase16 = (const unsigned short*)Asrc +
                                    (size_t)(row0 + sr) * ASTR + sc8;
    const float* abase32 = (const float*)Asrc + (size_t)(row0 + sr) * ASTR + sc8;

    f32x4 acc[4][NT];
#pragma unroll
    for (int a = 0; a < 4; ++a)
#pragma unroll
        for (int c = 0; c < NT; ++c) acc[a][c] = (f32x4){0.f, 0.f, 0.f, 0.f};

    uint4 rA = make_uint4(0u,0u,0u,0u);
    float4 rAf0 = make_float4(0,0,0,0), rAf1 = make_float4(0,0,0,0);
    uint4 rB[NPB];

    auto loadR = [&](int t) {
        const int gk = t * 32;
        if constexpr (SRCF32) {
            if (gk + sc8 < ASTR) {
                rAf0 = *(const float4*)(abase32 + gk);
                rAf1 = *(const float4*)(abase32 + gk + 4);
            } else {
                rAf0 = make_float4(0,0,0,0);
                rAf1 = make_float4(0,0,0,0);
            }
        } else {
            rA = *(const uint4*)(abase16 + gk);
        }
#pragma unroll
        for (int p = 0; p < NPB; ++p) {
            int rp = p * 128 + sr;
            if (rp < OP)
                rB[p] = *(const uint4*)(Wp + (size_t)(cbase + rp) * KP + gk + sc8);
        }
    };

    auto writeStage = [&](int bsel) {
        if constexpr (SRCF32) {
            union { unsigned short us[8]; uint4 v; } t;
            t.us[0] = f2bf(rAf0.x); t.us[1] = f2bf(rAf0.y);
            t.us[2] = f2bf(rAf0.z); t.us[3] = f2bf(rAf0.w);
            t.us[4] = f2bf(rAf1.x); t.us[5] = f2bf(rAf1.y);
            t.us[6] = f2bf(rAf1.z); t.us[7] = f2bf(rAf1.w);
            *(uint4*)&Al[bsel][sr * 40 + sc8] = t.v;
        } else {
            *(uint4*)&Al[bsel][sr * 40 + sc8] = rA;
        }
#pragma unroll
        for (int p = 0; p < NPB; ++p) {
            int rp = p * 128 + sr;
            if (rp < OP)
                *(uint4*)&Wl[bsel][rp * 40 + sc8] = rB[p];
        }
    };

    // prologue
    loadR(0);
    writeStage(0);
    if (NKT > 1) loadR(1);
    __syncthreads();

    for (int t = 0; t < NKT; ++t) {
        const int bsel = t & 1;
        bf16x8 afr[4], bfr[NT];
#pragma unroll
        for (int a = 0; a < 4; ++a)
            afr[a] = *(const bf16x8*)&Al[bsel][(wr * 64 + a * 16 + lc) * 40 + lg * 8];
#pragma unroll
        for (int c = 0; c < NT; ++c)
            bfr[c] = *(const bf16x8*)&Wl[bsel][(wc * NT * 16 + c * 16 + lc) * 40 + lg * 8];
#pragma unroll
        for (int a = 0; a < 4; ++a)
#pragma unroll
            for (int c = 0; c < NT; ++c)
                acc[a][c] = __builtin_amdgcn_mfma_f32_16x16x32_bf16(afr[a], bfr[c], acc[a][c], 0, 0, 0);

        if (t + 1 < NKT) {
            writeStage(bsel ^ 1);
            if (t + 2 < NKT) loadR(t + 2);
        }
        __syncthreads();
    }

    // ---------------- epilogue ----------------
    if constexpr (LN) {
        if constexpr (HASBIAS) {
#pragma unroll
            for (int c = 0; c < NT; ++c) {
                int col = wc * NT * 16 + c * 16 + lc;
                float bv = (col < OREAL) ? bias[col] : 0.f;
#pragma unroll
                for (int a = 0; a < 4; ++a)
#pragma unroll
                    for (int r = 0; r < 4; ++r) acc[a][c][r] += bv;
            }
        }
        // per-row partial sums over this wave's columns (pad cols are exact 0)
        float ps1[4][4], ps2[4][4];
#pragma unroll
        for (int a = 0; a < 4; ++a)
#pragma unroll
            for (int r = 0; r < 4; ++r) { ps1[a][r] = 0.f; ps2[a][r] = 0.f; }
#pragma unroll
        for (int a = 0; a < 4; ++a)
#pragma unroll
            for (int c = 0; c < NT; ++c)
#pragma unroll
                for (int r = 0; r < 4; ++r) {
                    float v = acc[a][c][r];
                    ps1[a][r] += v;
                    ps2[a][r] = __fmaf_rn(v, v, ps2[a][r]);
                }
#pragma unroll
        for (int m = 1; m < 16; m <<= 1)
#pragma unroll
            for (int a = 0; a < 4; ++a)
#pragma unroll
                for (int r = 0; r < 4; ++r) {
                    ps1[a][r] += __shfl_xor(ps1[a][r], m);
                    ps2[a][r] += __shfl_xor(ps2[a][r], m);
                }
        if (lc == 0) {
#pragma unroll
            for (int a = 0; a < 4; ++a)
#pragma unroll
                for (int r = 0; r < 4; ++r) {
                    int row = wr * 64 + a * 16 + lg * 4 + r;
                    lnP[row * 4 + wc]       = ps1[a][r];
                    lnP[512 + row * 4 + wc] = ps2[a][r];
                }
        }
        __syncthreads();
        if (tid < 128) {
            float s1 = lnP[tid * 4] + lnP[tid * 4 + 1] + lnP[tid * 4 + 2] + lnP[tid * 4 + 3];
            float s2 = lnP[512 + tid * 4] + lnP[512 + tid * 4 + 1] +
                       lnP[512 + tid * 4 + 2] + lnP[512 + tid * 4 + 3];
            float mu = s1 * (1.f / OREAL);
            float var = fmaxf(s2 * (1.f / OREAL) - mu * mu, 0.f);
            lnMR[tid] = mu;
            lnMR[128 + tid] = rsqrtf(var + EPS_LN);
        }
        __syncthreads();

        float gcol[NT], bcol[NT];
#pragma unroll
        for (int c = 0; c < NT; ++c) {
            int col = wc * NT * 16 + c * 16 + lc;
            gcol[c] = (col < OREAL) ? gam[col] : 0.f;
            bcol[c] = (col < OREAL) ? bet[col] : 0.f;
        }

        float asum = 0.f;
        unsigned short* outp = (unsigned short*)Aout;
#pragma unroll
        for (int a = 0; a < 4; ++a)
#pragma unroll
            for (int r = 0; r < 4; ++r) {
                int rl = wr * 64 + a * 16 + lg * 4 + r;
                float mu = lnMR[rl], rs = lnMR[128 + rl];
                size_t rowoff = (size_t)(row0 + rl) * OSTRIDE;
#pragma unroll
                for (int c = 0; c < NT; ++c) {
                    int col = wc * NT * 16 + c * 16 + lc;
                    if (col < OSTRIDE) {
                        unsigned short outv = 0;
                        if (col < OREAL) {
                            float v = (acc[a][c][r] - mu) * rs * gcol[c] + bcol[c];
                            float mz = mish_f(v);
                            if (ABS) asum += fabsf(mz);
                            outv = f2bf(mz);
                        }
                        outp[rowoff + col] = outv;
                    }
                }
            }

        if constexpr (ABS) {
#pragma unroll
            for (int m = 1; m < 64; m <<= 1) asum += __shfl_xor(asum, m);
            if (lane == 0) wsum[wave] = asum;
            __syncthreads();
            if (tid == 0) {
                float s = 0.f;
                for (int w = 0; w < 8; ++w) s += wsum[w];
                partials[blockIdx.x] = s;
            }
        }
    } else {
        // final layer: bias + sigmoid, fp32 out, stride 784
        float* outp = (float*)Aout;
#pragma unroll
        for (int c = 0; c < NT; ++c) {
            int gcolI = cbase + wc * NT * 16 + c * 16 + lc;
            float bv = (gcolI < OREAL) ? bias[gcolI] : 0.f;
#pragma unroll
            for (int a = 0; a < 4; ++a)
#pragma unroll
                for (int r = 0; r < 4; ++r) {
                    if (gcolI < OREAL) {
                        int rl = wr * 64 + a * 16 + lg * 4 + r;
                        float v = acc[a][c][r] + bv;
                        float s = 1.f / (1.f + __expf(-v));
                        outp[(size_t)(row0 + rl) * 784 + gcolI] = s;
                    }
                }
        }
    }
}

// ---------------- deterministic reduction of |latent| partials ----------------
__global__ void reduce_abs(const float* __restrict__ partials, float* __restrict__ out) {
    __shared__ float sm[256];
    float s = 0.f;
    for (int i = threadIdx.x; i < 512; i += 256) s += partials[i];
    sm[threadIdx.x] = s;
    __syncthreads();
    for (int step = 128; step > 0; step >>= 1) {
        if (threadIdx.x < step) sm[threadIdx.x] += sm[threadIdx.x + step];
        __syncthreads();
    }
    if (threadIdx.x == 0) out[0] = sm[0];
}

extern "C" void kernel_launch(void* const* d_in, const int* in_sizes, int n_in,
                              void* d_out, int out_size, void* d_ws, size_t ws_size,
                              hipStream_t stream)
{
    const float* x   = (const float*)d_in[0];
    const float* W1  = (const float*)d_in[1];
    const float* g1  = (const float*)d_in[2];
    const float* b1  = (const float*)d_in[3];
    const float* W2  = (const float*)d_in[4];
    const float* g2  = (const float*)d_in[5];
    const float* b2  = (const float*)d_in[6];
    const float* W3  = (const float*)d_in[7];
    const float* b3  = (const float*)d_in[8];
    const float* gh  = (const float*)d_in[9];
    const float* bh  = (const float*)d_in[10];
    const float* D1  = (const float*)d_in[11];
    const float* g3  = (const float*)d_in[12];
    const float* b3n = (const float*)d_in[13];
    const float* D2  = (const float*)d_in[14];
    const float* g4  = (const float*)d_in[15];
    const float* b4  = (const float*)d_in[16];
    const float* D3  = (const float*)d_in[17];
    const float* bo  = (const float*)d_in[18];

    char* ws = (char*)d_ws;
    size_t off = 0;
    auto alloc = [&](size_t bytes) -> char* {
        char* p = ws + off;
        off += (bytes + 255) & ~(size_t)255;
        return p;
    };
    unsigned short* W1p = (unsigned short*)alloc((size_t)512 * 800 * 2);
    unsigned short* W2p = (unsigned short*)alloc((size_t)320 * 512 * 2);
    unsigned short* W3p = (unsigned short*)alloc((size_t)128 * 288 * 2);
    unsigned short* D1p = (unsigned short*)alloc((size_t)320 * 128 * 2);
    unsigned short* D2p = (unsigned short*)alloc((size_t)512 * 288 * 2);
    unsigned short* D3p = (unsigned short*)alloc((size_t)896 * 512 * 2);
    unsigned short* actP = (unsigned short*)alloc((size_t)B_ROWS * 512 * 2);
    unsigned short* actQ = (unsigned short*)alloc((size_t)B_ROWS * 288 * 2);
    unsigned short* actL = (unsigned short*)alloc((size_t)B_ROWS * 128 * 2);
    float* partials = (float*)alloc(512 * 4);

    CvtArgs ca;
    ca.src[0] = W1; ca.dst[0] = W1p; ca.O[0] = 512; ca.K[0] = 784; ca.KP[0] = 800;
    ca.src[1] = W2; ca.dst[1] = W2p; ca.O[1] = 264; ca.K[1] = 512; ca.KP[1] = 512;
    ca.src[2] = W3; ca.dst[2] = W3p; ca.O[2] = 128; ca.K[2] = 264; ca.KP[2] = 288;
    ca.src[3] = D1; ca.dst[3] = D1p; ca.O[3] = 264; ca.K[3] = 128; ca.KP[3] = 128;
    ca.src[4] = D2; ca.dst[4] = D2p; ca.O[4] = 512; ca.K[4] = 264; ca.KP[4] = 288;
    ca.src[5] = D3; ca.dst[5] = D3p; ca.O[5] = 784; ca.K[5] = 512; ca.KP[5] = 512;
    ca.base[0] = 0;    ca.base[1] = 512;  ca.base[2] = 832;
    ca.base[3] = 960;  ca.base[4] = 1280; ca.base[5] = 1792; ca.base[6] = 2688;
    wpad_kernel<<<2688, 256, 0, stream>>>(ca);

    const int NB = B_ROWS / 128;  // 512

    // L1: x[.,784] @ W1^T -> 512, LN, mish
    layer2<800, 784, 512, 512, 512, 25, true, false, false, true>
        <<<NB, 512, 0, stream>>>(x, W1p, g1, b1, nullptr, actP, nullptr);
    // L2: 512 -> 264 (pad 320), LN, mish, store stride 288
    layer2<512, 512, 320, 264, 288, 16, false, false, false, true>
        <<<NB, 512, 0, stream>>>(actP, W2p, g2, b2, nullptr, actQ, nullptr);
    // L3: 264(288) -> 128, +b3, LN, mish, abs-partials
    layer2<288, 288, 128, 128, 128, 9, false, true, true, true>
        <<<NB, 512, 0, stream>>>(actQ, W3p, gh, bh, b3, actL, partials);
    // L4: 128 -> 264 (pad 320), LN, mish, store stride 288
    layer2<128, 128, 320, 264, 288, 4, false, false, false, true>
        <<<NB, 512, 0, stream>>>(actL, D1p, g3, b3n, nullptr, actQ, nullptr);
    // L5: 264(288) -> 512, LN, mish
    layer2<288, 288, 512, 512, 512, 9, false, false, false, true>
        <<<NB, 512, 0, stream>>>(actQ, D2p, g4, b4, nullptr, actP, nullptr);
    // L6: 512 -> 784 (2 col-blocks of 448), +bo, sigmoid, fp32 out
    dim3 g6(NB, 2);
    layer2<512, 512, 448, 784, 784, 16, false, true, false, false>
        <<<g6, 512, 0, stream>>>(actP, D3p, nullptr, nullptr, bo, d_out, nullptr);

    reduce_abs<<<1, 256, 0, stream>>>(partials, (float*)d_out + (size_t)B_ROWS * 784);
}

// Round 3
// 479.463 us; speedup vs baseline: 1.7182x; 1.2319x over previous
//
#include <hip/hip_runtime.h>

// AutoEncoder fused pipeline v3, bf16 MFMA (gfx950).
// 1024-thread blocks (16 waves, 2 row x 8 col), 128-row x OP tiles,
// global_load_lds staging with pre-swizzled source, XOR-swizzled LDS.

typedef short bf16x8 __attribute__((ext_vector_type(8)));
typedef float f32x4  __attribute__((ext_vector_type(4)));

#define B_ROWS 65536
#define EPS_LN 1e-5f

static __device__ __forceinline__ unsigned short f2bf(float f) {
    union { float f; unsigned u; } v; v.f = f;
    unsigned r = v.u + 0x7FFFu + ((v.u >> 16) & 1u);   // RNE
    return (unsigned short)(r >> 16);
}

static __device__ __forceinline__ float mish_f(float x) {
    if (x > 15.f) return x;
    float u = __expf(x);
    float p = __fmaf_rn(u, u, 2.f * u);
    return x * (p / (p + 2.f));
}

// direct global->LDS, 16B per lane; LDS base must be wave-uniform
static __device__ __forceinline__ void glds16(const void* g, void* l) {
    typedef __attribute__((address_space(3))) unsigned lds_u32;
    typedef __attribute__((address_space(1))) const unsigned glb_u32;
    lds_u32* lp = (lds_u32*)l;
    unsigned lofs = __builtin_amdgcn_readfirstlane((unsigned)(unsigned long long)lp);
    lp = (lds_u32*)(unsigned long long)lofs;
    __builtin_amdgcn_global_load_lds((glb_u32*)g, lp, 16, 0, 0);
}

// ---------------- padded weight fp32->bf16 conversion ----------------
struct CvtArgs {
    const float* src[6];
    unsigned short* dst[6];
    int O[6], K[6], KP[6];
    int base[7];
};

__global__ void wpad_kernel(CvtArgs a) {
    int b = blockIdx.x;
    int seg = 0;
    while (b >= a.base[seg + 1]) ++seg;
    int r = b - a.base[seg];
    int O = a.O[seg], K = a.K[seg], KP = a.KP[seg];
    const float* s = a.src[seg];
    unsigned short* d = a.dst[seg];
    for (int c = threadIdx.x; c < KP; c += 256) {
        unsigned short v = 0;
        if (r < O && c < K) v = f2bf(s[(size_t)r * K + c]);
        d[(size_t)r * KP + c] = v;
    }
}

// ---------------- fused layer kernel ----------------
// Block: 1024 threads = 16 waves (2 row-groups x 8 col-groups).
// Tile: 128 rows x OP cols; wave tile 64 x (OP/8); BK=32.
// LDS layout swizzle: 16B slot' = slot ^ ((row>>1)&3) within 64B rows.
template<int KP, int ASTR, int KREAL, int OP, int OREAL, int OSTRIDE, int NKT,
         bool SRCF32, bool HASBIAS, bool ABS, bool LN>
__global__ __launch_bounds__(1024, 4)
void layer3(const void* __restrict__ Asrc,
            const unsigned short* __restrict__ Wp,
            const float* __restrict__ gam,
            const float* __restrict__ bet,
            const float* __restrict__ bias,
            void* __restrict__ Aout,
            float* __restrict__ partials,
            int cbase)
{
    constexpr int NT     = OP / 128;       // frags per col-wave
    constexpr int NCH_W  = OP / 16;        // 1KB wave-chunks in W tile
    constexpr int ABYTES = 128 * 64;       // 8 KB per A buffer
    constexpr int WBYTES = OP * 64;

    __shared__ __align__(16) char smem[2 * ABYTES + 2 * WBYTES];

    const int tid  = threadIdx.x;
    const int wave = tid >> 6, lane = tid & 63;
    const int wr = wave >> 3, wc = wave & 7;
    const int lg = lane >> 4, lc = lane & 15;
    const int row0 = blockIdx.x * 128;

    // ---- precomputed per-lane staging offsets (pre-swizzled global source) ----
    size_t goW[2];
    int    loW[2];
#pragma unroll
    for (int i = 0; i < 2; ++i) {
        int j = wave + 16 * i;
        if (j < NCH_W) {
            int q = j * 64 + lane;
            int r = q >> 2;
            int sg = (q & 3) ^ ((r >> 1) & 3);
            goW[i] = ((size_t)(cbase + r) * KP + sg * 8) * 2;
            loW[i] = 2 * ABYTES + j * 1024;
        } else { goW[i] = 0; loW[i] = 0; }
    }
    size_t goA = 0; int loA = 0;
    if constexpr (!SRCF32) {
        if (wave < 8) {
            int q = wave * 64 + lane;
            int r = q >> 2;
            int sg = (q & 3) ^ ((r >> 1) & 3);
            goA = ((size_t)(row0 + r) * ASTR + sg * 8) * 2;
            loA = wave * 1024;
        }
    }

    const char* Wg = (const char*)Wp;
    const char* Ag = (const char*)Asrc;

    // ---- L1 fp32 A path: reg-staged (conversion needed) ----
    float4 rA0 = make_float4(0,0,0,0), rA1 = make_float4(0,0,0,0);
    const int ar = tid >> 2, as = tid & 3;          // threads 0..511
    const float* axp = (const float*)Asrc + (size_t)(row0 + ar) * ASTR + as * 8;
    const int aswz = ar * 64 + ((as ^ ((ar >> 1) & 3)) << 4);

    auto loadA1 = [&](int t) {
        int c0 = t * 32 + as * 8;
        rA0 = (c0     < KREAL) ? *(const float4*)(axp + t * 32)     : make_float4(0,0,0,0);
        rA1 = (c0 + 4 < KREAL) ? *(const float4*)(axp + t * 32 + 4) : make_float4(0,0,0,0);
    };
    auto pubA = [&](int bsel) {
        union { unsigned short us[8]; uint4 v; } u;
        u.us[0] = f2bf(rA0.x); u.us[1] = f2bf(rA0.y);
        u.us[2] = f2bf(rA0.z); u.us[3] = f2bf(rA0.w);
        u.us[4] = f2bf(rA1.x); u.us[5] = f2bf(rA1.y);
        u.us[6] = f2bf(rA1.z); u.us[7] = f2bf(rA1.w);
        *(uint4*)(smem + bsel * ABYTES + aswz) = u.v;
    };
    auto stageW = [&](int t, int bsel) {
#pragma unroll
        for (int i = 0; i < 2; ++i)
            if (wave + 16 * i < NCH_W)
                glds16(Wg + goW[i] + (size_t)t * 64, smem + loW[i] + bsel * WBYTES);
        if constexpr (!SRCF32) {
            if (wave < 8)
                glds16(Ag + goA + (size_t)t * 64, smem + loA + bsel * ABYTES);
        }
    };

    // ---- prologue ----
    stageW(0, 0);
    if constexpr (SRCF32) {
        if (tid < 512) { loadA1(0); pubA(0); if (NKT > 1) loadA1(1); }
    }
    __syncthreads();

    // ---- main K loop ----
    f32x4 acc[4][NT];
#pragma unroll
    for (int a = 0; a < 4; ++a)
#pragma unroll
        for (int c = 0; c < NT; ++c) acc[a][c] = (f32x4){0.f, 0.f, 0.f, 0.f};

    const int fswz = ((lg ^ ((lc >> 1) & 3)) << 4);

    for (int t = 0; t < NKT; ++t) {
        const int bsel = t & 1;
        if (t + 1 < NKT) stageW(t + 1, bsel ^ 1);

        const char* Ab = smem + bsel * ABYTES + (wr * 64 + lc) * 64 + fswz;
        const char* Bb = smem + 2 * ABYTES + bsel * WBYTES + (wc * NT * 16 + lc) * 64 + fswz;
        bf16x8 afr[4], bfr[NT];
#pragma unroll
        for (int a = 0; a < 4; ++a) afr[a] = *(const bf16x8*)(Ab + a * 1024);
#pragma unroll
        for (int c = 0; c < NT; ++c) bfr[c] = *(const bf16x8*)(Bb + c * 1024);

        if constexpr (SRCF32) {
            if (tid < 512) {
                if (t + 1 < NKT) pubA(bsel ^ 1);
                if (t + 2 < NKT) loadA1(t + 2);
            }
        }
        __builtin_amdgcn_sched_barrier(0);
#pragma unroll
        for (int c = 0; c < NT; ++c)
#pragma unroll
            for (int a = 0; a < 4; ++a)
                acc[a][c] = __builtin_amdgcn_mfma_f32_16x16x32_bf16(afr[a], bfr[c], acc[a][c], 0, 0, 0);
        __syncthreads();
    }

    // ---- epilogue ----
    if constexpr (LN) {
        if constexpr (HASBIAS) {
#pragma unroll
            for (int c = 0; c < NT; ++c) {
                int col = wc * NT * 16 + c * 16 + lc;
                float bv = (col < OREAL) ? bias[col] : 0.f;
#pragma unroll
                for (int a = 0; a < 4; ++a)
#pragma unroll
                    for (int r = 0; r < 4; ++r) acc[a][c][r] += bv;
            }
        }
        // per-(row, col-wave) partial sums; pad cols are exact zeros
        float ps1[4][4], ps2[4][4];
#pragma unroll
        for (int a = 0; a < 4; ++a)
#pragma unroll
            for (int r = 0; r < 4; ++r) { ps1[a][r] = 0.f; ps2[a][r] = 0.f; }
#pragma unroll
        for (int a = 0; a < 4; ++a)
#pragma unroll
            for (int c = 0; c < NT; ++c)
#pragma unroll
                for (int r = 0; r < 4; ++r) {
                    float v = acc[a][c][r];
                    ps1[a][r] += v;
                    ps2[a][r] = __fmaf_rn(v, v, ps2[a][r]);
                }
#pragma unroll
        for (int m = 1; m < 16; m <<= 1)
#pragma unroll
            for (int a = 0; a < 4; ++a)
#pragma unroll
                for (int r = 0; r < 4; ++r) {
                    ps1[a][r] += __shfl_xor(ps1[a][r], m);
                    ps2[a][r] += __shfl_xor(ps2[a][r], m);
                }

        float* lnP  = (float*)smem;          // [128][8] s1, then s2 at +1024
        float* lnMR = (float*)smem + 2048;   // [256]
        float* wsumP= (float*)smem + 2304;   // [16]

        if (lc == 0) {
#pragma unroll
            for (int a = 0; a < 4; ++a)
#pragma unroll
                for (int r = 0; r < 4; ++r) {
                    int row = wr * 64 + a * 16 + lg * 4 + r;
                    lnP[row * 8 + wc]        = ps1[a][r];
                    lnP[1024 + row * 8 + wc] = ps2[a][r];
                }
        }
        __syncthreads();
        if (tid < 128) {
            float s1 = 0.f, s2 = 0.f;
#pragma unroll
            for (int w = 0; w < 8; ++w) { s1 += lnP[tid * 8 + w]; s2 += lnP[1024 + tid * 8 + w]; }
            float mu = s1 * (1.f / OREAL);
            float var = fmaxf(s2 * (1.f / OREAL) - mu * mu, 0.f);
            lnMR[tid]       = mu;
            lnMR[128 + tid] = rsqrtf(var + EPS_LN);
        }
        __syncthreads();

        float gcol[NT], bcol[NT];
#pragma unroll
        for (int c = 0; c < NT; ++c) {
            int col = wc * NT * 16 + c * 16 + lc;
            gcol[c] = (col < OREAL) ? gam[col] : 0.f;
            bcol[c] = (col < OREAL) ? bet[col] : 0.f;
        }

        float asum = 0.f;
        unsigned short* outp = (unsigned short*)Aout;
#pragma unroll
        for (int a = 0; a < 4; ++a)
#pragma unroll
            for (int r = 0; r < 4; ++r) {
                int rl = wr * 64 + a * 16 + lg * 4 + r;
                float mu = lnMR[rl], rs = lnMR[128 + rl];
                size_t rowoff = (size_t)(row0 + rl) * OSTRIDE;
#pragma unroll
                for (int c = 0; c < NT; ++c) {
                    int col = wc * NT * 16 + c * 16 + lc;
                    if (col < OSTRIDE) {
                        unsigned short outv = 0;
                        if (col < OREAL) {
                            float v = (acc[a][c][r] - mu) * rs * gcol[c] + bcol[c];
                            float mz = mish_f(v);
                            if (ABS) asum += fabsf(mz);
                            outv = f2bf(mz);
                        }
                        outp[rowoff + col] = outv;
                    }
                }
            }

        if constexpr (ABS) {
#pragma unroll
            for (int m = 1; m < 64; m <<= 1) asum += __shfl_xor(asum, m);
            if (lane == 0) wsumP[wave] = asum;
            __syncthreads();
            if (tid == 0) {
                float s = 0.f;
                for (int w = 0; w < 16; ++w) s += wsumP[w];
                partials[blockIdx.x] = s;
            }
        }
    } else {
        // final layer: bias + sigmoid, fp32 out
        float* outp = (float*)Aout;
#pragma unroll
        for (int c = 0; c < NT; ++c) {
            int col = cbase + wc * NT * 16 + c * 16 + lc;
            bool ok = col < OREAL;
            float bv = ok ? bias[col] : 0.f;
#pragma unroll
            for (int a = 0; a < 4; ++a)
#pragma unroll
                for (int r = 0; r < 4; ++r) {
                    if (ok) {
                        int rl = wr * 64 + a * 16 + lg * 4 + r;
                        float v = acc[a][c][r] + bv;
                        outp[(size_t)(row0 + rl) * OSTRIDE + col] = 1.f / (1.f + __expf(-v));
                    }
                }
        }
    }
}

// ---------------- deterministic reduction of |latent| partials ----------------
__global__ void reduce_abs(const float* __restrict__ partials, float* __restrict__ out) {
    __shared__ float sm[256];
    float s = 0.f;
    for (int i = threadIdx.x; i < 512; i += 256) s += partials[i];
    sm[threadIdx.x] = s;
    __syncthreads();
    for (int step = 128; step > 0; step >>= 1) {
        if (threadIdx.x < step) sm[threadIdx.x] += sm[threadIdx.x + step];
        __syncthreads();
    }
    if (threadIdx.x == 0) out[0] = sm[0];
}

extern "C" void kernel_launch(void* const* d_in, const int* in_sizes, int n_in,
                              void* d_out, int out_size, void* d_ws, size_t ws_size,
                              hipStream_t stream)
{
    const float* x   = (const float*)d_in[0];
    const float* W1  = (const float*)d_in[1];
    const float* g1  = (const float*)d_in[2];
    const float* b1  = (const float*)d_in[3];
    const float* W2  = (const float*)d_in[4];
    const float* g2  = (const float*)d_in[5];
    const float* b2  = (const float*)d_in[6];
    const float* W3  = (const float*)d_in[7];
    const float* b3  = (const float*)d_in[8];
    const float* gh  = (const float*)d_in[9];
    const float* bh  = (const float*)d_in[10];
    const float* D1  = (const float*)d_in[11];
    const float* g3  = (const float*)d_in[12];
    const float* b3n = (const float*)d_in[13];
    const float* D2  = (const float*)d_in[14];
    const float* g4  = (const float*)d_in[15];
    const float* b4  = (const float*)d_in[16];
    const float* D3  = (const float*)d_in[17];
    const float* bo  = (const float*)d_in[18];

    char* ws = (char*)d_ws;
    size_t off = 0;
    auto alloc = [&](size_t bytes) -> char* {
        char* p = ws + off;
        off += (bytes + 255) & ~(size_t)255;
        return p;
    };
    unsigned short* W1p = (unsigned short*)alloc((size_t)512 * 800 * 2);
    unsigned short* W2p = (unsigned short*)alloc((size_t)384 * 512 * 2);
    unsigned short* W3p = (unsigned short*)alloc((size_t)128 * 288 * 2);
    unsigned short* D1p = (unsigned short*)alloc((size_t)384 * 128 * 2);
    unsigned short* D2p = (unsigned short*)alloc((size_t)512 * 288 * 2);
    unsigned short* D3p = (unsigned short*)alloc((size_t)896 * 512 * 2);
    unsigned short* actP = (unsigned short*)alloc((size_t)B_ROWS * 512 * 2);
    unsigned short* actQ = (unsigned short*)alloc((size_t)B_ROWS * 288 * 2);
    unsigned short* actL = (unsigned short*)alloc((size_t)B_ROWS * 128 * 2);
    float* partials = (float*)alloc(512 * 4);

    CvtArgs ca;
    ca.src[0] = W1; ca.dst[0] = W1p; ca.O[0] = 512; ca.K[0] = 784; ca.KP[0] = 800;
    ca.src[1] = W2; ca.dst[1] = W2p; ca.O[1] = 264; ca.K[1] = 512; ca.KP[1] = 512;
    ca.src[2] = W3; ca.dst[2] = W3p; ca.O[2] = 128; ca.K[2] = 264; ca.KP[2] = 288;
    ca.src[3] = D1; ca.dst[3] = D1p; ca.O[3] = 264; ca.K[3] = 128; ca.KP[3] = 128;
    ca.src[4] = D2; ca.dst[4] = D2p; ca.O[4] = 512; ca.K[4] = 264; ca.KP[4] = 288;
    ca.src[5] = D3; ca.dst[5] = D3p; ca.O[5] = 784; ca.K[5] = 512; ca.KP[5] = 512;
    ca.base[0] = 0;    ca.base[1] = 512;  ca.base[2] = 896;
    ca.base[3] = 1024; ca.base[4] = 1408; ca.base[5] = 1920; ca.base[6] = 2816;
    wpad_kernel<<<2816, 256, 0, stream>>>(ca);

    const int NB = B_ROWS / 128;  // 512

    // L1: x[.,784] @ W1^T -> 512, LN, mish
    layer3<800, 784, 784, 512, 512, 512, 25, true,  false, false, true>
        <<<NB, 1024, 0, stream>>>(x, W1p, g1, b1, nullptr, actP, nullptr, 0);
    // L2: 512 -> 264 (OP 384), LN, mish, store stride 288
    layer3<512, 512, 512, 384, 264, 288, 16, false, false, false, true>
        <<<NB, 1024, 0, stream>>>(actP, W2p, g2, b2, nullptr, actQ, nullptr, 0);
    // L3: 288 -> 128, +b3, LN, mish, abs-partials
    layer3<288, 288, 288, 128, 128, 128, 9,  false, true,  true,  true>
        <<<NB, 1024, 0, stream>>>(actQ, W3p, gh, bh, b3, actL, partials, 0);
    // L4: 128 -> 264 (OP 384), LN, mish, store stride 288
    layer3<128, 128, 128, 384, 264, 288, 4,  false, false, false, true>
        <<<NB, 1024, 0, stream>>>(actL, D1p, g3, b3n, nullptr, actQ, nullptr, 0);
    // L5: 288 -> 512, LN, mish
    layer3<288, 288, 288, 512, 512, 512, 9,  false, false, false, true>
        <<<NB, 1024, 0, stream>>>(actQ, D2p, g4, b4, nullptr, actP, nullptr, 0);
    // L6: 512 -> 784, +bo, sigmoid, fp32 out (two col-ranges)
    layer3<512, 512, 512, 512, 784, 784, 16, false, true,  false, false>
        <<<NB, 1024, 0, stream>>>(actP, D3p, nullptr, nullptr, bo, d_out, nullptr, 0);
    layer3<512, 512, 512, 384, 784, 784, 16, false, true,  false, false>
        <<<NB, 1024, 0, stream>>>(actP, D3p, nullptr, nullptr, bo, d_out, nullptr, 512);

    reduce_abs<<<1, 256, 0, stream>>>(partials, (float*)d_out + (size_t)B_ROWS * 784);
}

// Round 4
// 479.379 us; speedup vs baseline: 1.7185x; 1.0002x over previous
//
#include <hip/hip_runtime.h>

// AutoEncoder fused pipeline v4, bf16 MFMA (gfx950).
// 1024-thread blocks (16 waves, 2 row x 8 col), 128-row x OP tiles, BK=32.
// Depth-3 LDS pipeline with raw s_barrier + counted s_waitcnt vmcnt(N)
// (never drains to 0 in the main loop). XOR-swizzled LDS, glds staging.

typedef short bf16x8 __attribute__((ext_vector_type(8)));
typedef float f32x4  __attribute__((ext_vector_type(4)));

#define B_ROWS 65536
#define EPS_LN 1e-5f

static __device__ __forceinline__ unsigned short f2bf(float f) {
    union { float f; unsigned u; } v; v.f = f;
    unsigned r = v.u + 0x7FFFu + ((v.u >> 16) & 1u);   // RNE
    return (unsigned short)(r >> 16);
}

static __device__ __forceinline__ float mish_f(float x) {
    if (x > 15.f) return x;
    float u = __expf(x);
    float p = __fmaf_rn(u, u, 2.f * u);
    return x * (p / (p + 2.f));
}

// direct global->LDS, 16B per lane; LDS base must be wave-uniform
static __device__ __forceinline__ void glds16(const void* g, void* l) {
    typedef __attribute__((address_space(3))) unsigned lds_u32;
    typedef __attribute__((address_space(1))) const unsigned glb_u32;
    lds_u32* lp = (lds_u32*)l;
    unsigned lofs = __builtin_amdgcn_readfirstlane((unsigned)(unsigned long long)lp);
    lp = (lds_u32*)(unsigned long long)lofs;
    __builtin_amdgcn_global_load_lds((glb_u32*)g, lp, 16, 0, 0);
}

template<int N> __device__ __forceinline__ void vwait() {
    if constexpr      (N <= 0) asm volatile("s_waitcnt vmcnt(0)" ::: "memory");
    else if constexpr (N == 1) asm volatile("s_waitcnt vmcnt(1)" ::: "memory");
    else if constexpr (N == 2) asm volatile("s_waitcnt vmcnt(2)" ::: "memory");
    else if constexpr (N == 3) asm volatile("s_waitcnt vmcnt(3)" ::: "memory");
    else if constexpr (N == 4) asm volatile("s_waitcnt vmcnt(4)" ::: "memory");
    else if constexpr (N == 5) asm volatile("s_waitcnt vmcnt(5)" ::: "memory");
    else if constexpr (N == 6) asm volatile("s_waitcnt vmcnt(6)" ::: "memory");
    else if constexpr (N == 8) asm volatile("s_waitcnt vmcnt(8)" ::: "memory");
    else                       asm volatile("s_waitcnt vmcnt(63)" ::: "memory");
}

static __device__ __forceinline__ void barrier_raw() {
    asm volatile("" ::: "memory");
    __builtin_amdgcn_s_barrier();
    asm volatile("" ::: "memory");
}

// ---------------- padded weight fp32->bf16 conversion ----------------
struct CvtArgs {
    const float* src[6];
    unsigned short* dst[6];
    int O[6], K[6], KP[6];
    int base[7];
};

__global__ void wpad_kernel(CvtArgs a) {
    int b = blockIdx.x;
    int seg = 0;
    while (b >= a.base[seg + 1]) ++seg;
    int r = b - a.base[seg];
    int O = a.O[seg], K = a.K[seg], KP = a.KP[seg];
    const float* s = a.src[seg];
    unsigned short* d = a.dst[seg];
    for (int c = threadIdx.x; c < KP; c += 256) {
        unsigned short v = 0;
        if (r < O && c < K) v = f2bf(s[(size_t)r * K + c]);
        d[(size_t)r * KP + c] = v;
    }
}

// ---------------- fused layer kernel (depth-3 counted-vmcnt pipeline) ----------------
template<int KP, int ASTR, int KREAL, int OP, int OREAL, int OSTRIDE, int NKT,
         bool SRCF32, bool HASBIAS, bool ABS, bool LN>
__global__ __launch_bounds__(1024, 4)
void layer4(const void* __restrict__ Asrc,
            const unsigned short* __restrict__ Wp,
            const float* __restrict__ gam,
            const float* __restrict__ bet,
            const float* __restrict__ bias,
            void* __restrict__ Aout,
            float* __restrict__ partials,
            int cbase)
{
    constexpr int NT      = OP / 128;
    constexpr int NCH_W   = OP / 16;                       // 1KB W chunks/stage
    constexpr int NCH_TOT = NCH_W + (SRCF32 ? 0 : 8);      // + A chunks
    constexpr int MAXC    = (NCH_TOT + 15) / 16;
    constexpr int ABYTES  = 128 * 64;
    constexpr int WBYTES  = OP * 64;
    constexpr int WBASE   = 3 * ABYTES;
    constexpr int LVL     = (NCH_TOT - 1 - 0) / 16 + 1;    // chunks/wave, waves 0-7
    constexpr int LVH     = (NCH_TOT - 1 - 8) / 16 + 1;    // chunks/wave, waves 8-15

    __shared__ __align__(16) char smem[WBASE + 3 * WBYTES];

    const int tid  = threadIdx.x;
    const int wave = tid >> 6, lane = tid & 63;
    const int wr = wave >> 3, wc = wave & 7;
    const int lg = lane >> 4, lc = lane & 15;
    const int row0 = blockIdx.x * 128;

    // ---- per-chunk staging descriptors (pre-swizzled global source) ----
    const char* gp[MAXC];
    int lo[MAXC], lstr[MAXC];
#pragma unroll
    for (int i = 0; i < MAXC; ++i) {
        int c = wave + 16 * i;
        gp[i] = nullptr; lo[i] = 0; lstr[i] = 0;
        if (c < NCH_W) {
            int row = c * 16 + (lane >> 2);
            int sg = (lane & 3) ^ ((row >> 1) & 3);
            gp[i] = (const char*)Wp + ((size_t)(cbase + row) * KP + sg * 8) * 2;
            lo[i] = WBASE + c * 1024; lstr[i] = WBYTES;
        } else if (c < NCH_TOT) {
            int ca = c - NCH_W;
            int row = ca * 16 + (lane >> 2);
            int sg = (lane & 3) ^ ((row >> 1) & 3);
            gp[i] = (const char*)Asrc + ((size_t)(row0 + row) * ASTR + sg * 8) * 2;
            lo[i] = ca * 1024; lstr[i] = ABYTES;
        }
    }
    auto stage = [&](int t, int b) {
#pragma unroll
        for (int i = 0; i < MAXC; ++i) {
            int c = wave + 16 * i;
            if (c < NCH_TOT)
                glds16(gp[i] + (size_t)t * 64, smem + lo[i] + b * lstr[i]);
        }
    };

    // ---- L1 fp32 A path: reg-staged with conversion ----
    const int ar = tid >> 2, as = tid & 3;
    const float* axp = (const float*)Asrc + (size_t)(row0 + ar) * ASTR + as * 8;
    const int aswz = ar * 64 + ((as ^ ((ar >> 1) & 3)) << 4);
    float4 rA0 = make_float4(0,0,0,0), rA1 = make_float4(0,0,0,0);

    auto loadA1 = [&](int t) {
        int c0 = t * 32 + as * 8;
        rA0 = (c0     < KREAL) ? *(const float4*)(axp + t * 32)     : make_float4(0,0,0,0);
        rA1 = (c0 + 4 < KREAL) ? *(const float4*)(axp + t * 32 + 4) : make_float4(0,0,0,0);
    };
    auto pubA = [&](int b) {
        union { unsigned short us[8]; uint4 v; } u;
        u.us[0] = f2bf(rA0.x); u.us[1] = f2bf(rA0.y);
        u.us[2] = f2bf(rA0.z); u.us[3] = f2bf(rA0.w);
        u.us[4] = f2bf(rA1.x); u.us[5] = f2bf(rA1.y);
        u.us[6] = f2bf(rA1.z); u.us[7] = f2bf(rA1.w);
        *(uint4*)(smem + b * ABYTES + aswz) = u.v;
    };

    // ---- prologue ----
    stage(0, 0);
    if constexpr (SRCF32) { if (tid < 512) loadA1(0); }
    stage(1, 1);
    if constexpr (SRCF32) {
        if (tid < 512) {
            pubA(0);          // waits A(0) -> retires stage(0), keeps stage(1) in flight
            loadA1(1);
            asm volatile("s_waitcnt lgkmcnt(0)" ::: "memory");
        }
    }

    // ---- main K loop ----
    f32x4 acc[4][NT];
#pragma unroll
    for (int a = 0; a < 4; ++a)
#pragma unroll
        for (int c = 0; c < NT; ++c) acc[a][c] = (f32x4){0.f, 0.f, 0.f, 0.f};

    const int fswz = ((lg ^ ((lc >> 1) & 3)) << 4);

    int bc = 0, bp = 1, bs = 2;
    for (int t = 0; t < NKT; ++t) {
        if (t + 2 < NKT) stage(t + 2, bs);

        // gate: ensure stage(t) landed (in-order vmcnt retirement => exact counts)
        if constexpr (SRCF32) {
            if (wave >= 8) {          // low waves covered by pubA's implicit wait
                if      (t + 2 < NKT) vwait<2 * LVL>();
                else if (t + 1 < NKT) vwait<LVL>();
                else                  vwait<0>();
            }
        } else if constexpr (LVL == LVH) {
            if      (t + 2 < NKT) vwait<2 * LVL>();
            else if (t + 1 < NKT) vwait<LVL>();
            else                  vwait<0>();
        } else {
            if (wave < 8) {
                if      (t + 2 < NKT) vwait<2 * LVL>();
                else if (t + 1 < NKT) vwait<LVL>();
                else                  vwait<0>();
            } else {
                if      (t + 2 < NKT) vwait<2 * LVH>();
                else if (t + 1 < NKT) vwait<LVH>();
                else                  vwait<0>();
            }
        }
        barrier_raw();

        const char* Ab = smem + bc * ABYTES + (wr * 64 + lc) * 64 + fswz;
        const char* Bb = smem + WBASE + bc * WBYTES + (wc * NT * 16 + lc) * 64 + fswz;
        bf16x8 afr[4], bfr[NT];
#pragma unroll
        for (int a = 0; a < 4; ++a) afr[a] = *(const bf16x8*)(Ab + a * 1024);
#pragma unroll
        for (int c = 0; c < NT; ++c) bfr[c] = *(const bf16x8*)(Bb + c * 1024);

        if constexpr (SRCF32) {       // cvt VALU + ds_write overlap the MFMA pipe
            if (tid < 512) {
                if (t + 1 < NKT) pubA(bp);
                if (t + 2 < NKT) loadA1(t + 2);
            }
        }
#pragma unroll
        for (int c = 0; c < NT; ++c)
#pragma unroll
            for (int a = 0; a < 4; ++a)
                acc[a][c] = __builtin_amdgcn_mfma_f32_16x16x32_bf16(afr[a], bfr[c], acc[a][c], 0, 0, 0);

        if constexpr (SRCF32) asm volatile("s_waitcnt lgkmcnt(0)" ::: "memory");
        barrier_raw();
        int tmp = bc; bc = bp; bp = bs; bs = tmp;
    }

    // ---- epilogue ----
    if constexpr (LN) {
        if constexpr (HASBIAS) {
#pragma unroll
            for (int c = 0; c < NT; ++c) {
                int col = wc * NT * 16 + c * 16 + lc;
                float bv = (col < OREAL) ? bias[col] : 0.f;
#pragma unroll
                for (int a = 0; a < 4; ++a)
#pragma unroll
                    for (int r = 0; r < 4; ++r) acc[a][c][r] += bv;
            }
        }
        float ps1[4][4], ps2[4][4];
#pragma unroll
        for (int a = 0; a < 4; ++a)
#pragma unroll
            for (int r = 0; r < 4; ++r) { ps1[a][r] = 0.f; ps2[a][r] = 0.f; }
#pragma unroll
        for (int a = 0; a < 4; ++a)
#pragma unroll
            for (int c = 0; c < NT; ++c)
#pragma unroll
                for (int r = 0; r < 4; ++r) {
                    float v = acc[a][c][r];
                    ps1[a][r] += v;
                    ps2[a][r] = __fmaf_rn(v, v, ps2[a][r]);
                }
#pragma unroll
        for (int m = 1; m < 16; m <<= 1)
#pragma unroll
            for (int a = 0; a < 4; ++a)
#pragma unroll
                for (int r = 0; r < 4; ++r) {
                    ps1[a][r] += __shfl_xor(ps1[a][r], m);
                    ps2[a][r] += __shfl_xor(ps2[a][r], m);
                }

        float* lnP   = (float*)smem;          // [128][8] s1, s2 at +1024
        float* lnMR  = (float*)smem + 2048;   // [256]
        float* wsumP = (float*)smem + 2304;   // [16]

        if (lc == 0) {
#pragma unroll
            for (int a = 0; a < 4; ++a)
#pragma unroll
                for (int r = 0; r < 4; ++r) {
                    int row = wr * 64 + a * 16 + lg * 4 + r;
                    lnP[row * 8 + wc]        = ps1[a][r];
                    lnP[1024 + row * 8 + wc] = ps2[a][r];
                }
        }
        __syncthreads();
        if (tid < 128) {
            float s1 = 0.f, s2 = 0.f;
#pragma unroll
            for (int w = 0; w < 8; ++w) { s1 += lnP[tid * 8 + w]; s2 += lnP[1024 + tid * 8 + w]; }
            float mu = s1 * (1.f / OREAL);
            float var = fmaxf(s2 * (1.f / OREAL) - mu * mu, 0.f);
            lnMR[tid]       = mu;
            lnMR[128 + tid] = rsqrtf(var + EPS_LN);
        }
        __syncthreads();

        float gcol[NT], bcol[NT];
#pragma unroll
        for (int c = 0; c < NT; ++c) {
            int col = wc * NT * 16 + c * 16 + lc;
            gcol[c] = (col < OREAL) ? gam[col] : 0.f;
            bcol[c] = (col < OREAL) ? bet[col] : 0.f;
        }

        float asum = 0.f;
        unsigned short* outp = (unsigned short*)Aout;
#pragma unroll
        for (int a = 0; a < 4; ++a)
#pragma unroll
            for (int r = 0; r < 4; ++r) {
                int rl = wr * 64 + a * 16 + lg * 4 + r;
                float mu = lnMR[rl], rs = lnMR[128 + rl];
                size_t rowoff = (size_t)(row0 + rl) * OSTRIDE;
#pragma unroll
                for (int c = 0; c < NT; ++c) {
                    int col = wc * NT * 16 + c * 16 + lc;
                    if (col < OSTRIDE) {
                        unsigned short outv = 0;
                        if (col < OREAL) {
                            float v = (acc[a][c][r] - mu) * rs * gcol[c] + bcol[c];
                            float mz = mish_f(v);
                            if (ABS) asum += fabsf(mz);
                            outv = f2bf(mz);
                        }
                        outp[rowoff + col] = outv;
                    }
                }
            }

        if constexpr (ABS) {
#pragma unroll
            for (int m = 1; m < 64; m <<= 1) asum += __shfl_xor(asum, m);
            if (lane == 0) wsumP[wave] = asum;
            __syncthreads();
            if (tid == 0) {
                float s = 0.f;
                for (int w = 0; w < 16; ++w) s += wsumP[w];
                partials[blockIdx.x] = s;
            }
        }
    } else {
        float* outp = (float*)Aout;
#pragma unroll
        for (int c = 0; c < NT; ++c) {
            int col = cbase + wc * NT * 16 + c * 16 + lc;
            bool ok = col < OREAL;
            float bv = ok ? bias[col] : 0.f;
#pragma unroll
            for (int a = 0; a < 4; ++a)
#pragma unroll
                for (int r = 0; r < 4; ++r) {
                    if (ok) {
                        int rl = wr * 64 + a * 16 + lg * 4 + r;
                        float v = acc[a][c][r] + bv;
                        outp[(size_t)(row0 + rl) * OSTRIDE + col] = 1.f / (1.f + __expf(-v));
                    }
                }
        }
    }
}

// ---------------- deterministic reduction of |latent| partials ----------------
__global__ void reduce_abs(const float* __restrict__ partials, float* __restrict__ out) {
    __shared__ float sm[256];
    float s = 0.f;
    for (int i = threadIdx.x; i < 512; i += 256) s += partials[i];
    sm[threadIdx.x] = s;
    __syncthreads();
    for (int step = 128; step > 0; step >>= 1) {
        if (threadIdx.x < step) sm[threadIdx.x] += sm[threadIdx.x + step];
        __syncthreads();
    }
    if (threadIdx.x == 0) out[0] = sm[0];
}

extern "C" void kernel_launch(void* const* d_in, const int* in_sizes, int n_in,
                              void* d_out, int out_size, void* d_ws, size_t ws_size,
                              hipStream_t stream)
{
    const float* x   = (const float*)d_in[0];
    const float* W1  = (const float*)d_in[1];
    const float* g1  = (const float*)d_in[2];
    const float* b1  = (const float*)d_in[3];
    const float* W2  = (const float*)d_in[4];
    const float* g2  = (const float*)d_in[5];
    const float* b2  = (const float*)d_in[6];
    const float* W3  = (const float*)d_in[7];
    const float* b3  = (const float*)d_in[8];
    const float* gh  = (const float*)d_in[9];
    const float* bh  = (const float*)d_in[10];
    const float* D1  = (const float*)d_in[11];
    const float* g3  = (const float*)d_in[12];
    const float* b3n = (const float*)d_in[13];
    const float* D2  = (const float*)d_in[14];
    const float* g4  = (const float*)d_in[15];
    const float* b4  = (const float*)d_in[16];
    const float* D3  = (const float*)d_in[17];
    const float* bo  = (const float*)d_in[18];

    char* ws = (char*)d_ws;
    size_t off = 0;
    auto alloc = [&](size_t bytes) -> char* {
        char* p = ws + off;
        off += (bytes + 255) & ~(size_t)255;
        return p;
    };
    unsigned short* W1p = (unsigned short*)alloc((size_t)512 * 800 * 2);
    unsigned short* W2p = (unsigned short*)alloc((size_t)384 * 512 * 2);
    unsigned short* W3p = (unsigned short*)alloc((size_t)128 * 288 * 2);
    unsigned short* D1p = (unsigned short*)alloc((size_t)384 * 128 * 2);
    unsigned short* D2p = (unsigned short*)alloc((size_t)512 * 288 * 2);
    unsigned short* D3p = (unsigned short*)alloc((size_t)896 * 512 * 2);
    unsigned short* actP = (unsigned short*)alloc((size_t)B_ROWS * 512 * 2);
    unsigned short* actQ = (unsigned short*)alloc((size_t)B_ROWS * 288 * 2);
    unsigned short* actL = (unsigned short*)alloc((size_t)B_ROWS * 128 * 2);
    float* partials = (float*)alloc(512 * 4);

    CvtArgs ca;
    ca.src[0] = W1; ca.dst[0] = W1p; ca.O[0] = 512; ca.K[0] = 784; ca.KP[0] = 800;
    ca.src[1] = W2; ca.dst[1] = W2p; ca.O[1] = 264; ca.K[1] = 512; ca.KP[1] = 512;
    ca.src[2] = W3; ca.dst[2] = W3p; ca.O[2] = 128; ca.K[2] = 264; ca.KP[2] = 288;
    ca.src[3] = D1; ca.dst[3] = D1p; ca.O[3] = 264; ca.K[3] = 128; ca.KP[3] = 128;
    ca.src[4] = D2; ca.dst[4] = D2p; ca.O[4] = 512; ca.K[4] = 264; ca.KP[4] = 288;
    ca.src[5] = D3; ca.dst[5] = D3p; ca.O[5] = 784; ca.K[5] = 512; ca.KP[5] = 512;
    ca.base[0] = 0;    ca.base[1] = 512;  ca.base[2] = 896;
    ca.base[3] = 1024; ca.base[4] = 1408; ca.base[5] = 1920; ca.base[6] = 2816;
    wpad_kernel<<<2816, 256, 0, stream>>>(ca);

    const int NB = B_ROWS / 128;  // 512

    // L1: x[.,784] @ W1^T -> 512, LN, mish
    layer4<800, 784, 784, 512, 512, 512, 25, true,  false, false, true>
        <<<NB, 1024, 0, stream>>>(x, W1p, g1, b1, nullptr, actP, nullptr, 0);
    // L2: 512 -> 264 (OP 384), LN, mish, store stride 288
    layer4<512, 512, 512, 384, 264, 288, 16, false, false, false, true>
        <<<NB, 1024, 0, stream>>>(actP, W2p, g2, b2, nullptr, actQ, nullptr, 0);
    // L3: 288 -> 128, +b3, LN, mish, abs-partials
    layer4<288, 288, 288, 128, 128, 128, 9,  false, true,  true,  true>
        <<<NB, 1024, 0, stream>>>(actQ, W3p, gh, bh, b3, actL, partials, 0);
    // L4: 128 -> 264 (OP 384), LN, mish, store stride 288
    layer4<128, 128, 128, 384, 264, 288, 4,  false, false, false, true>
        <<<NB, 1024, 0, stream>>>(actL, D1p, g3, b3n, nullptr, actQ, nullptr, 0);
    // L5: 288 -> 512, LN, mish
    layer4<288, 288, 288, 512, 512, 512, 9,  false, false, false, true>
        <<<NB, 1024, 0, stream>>>(actQ, D2p, g4, b4, nullptr, actP, nullptr, 0);
    // L6: 512 -> 784, +bo, sigmoid, fp32 out (two col-ranges)
    layer4<512, 512, 512, 512, 784, 784, 16, false, true,  false, false>
        <<<NB, 1024, 0, stream>>>(actP, D3p, nullptr, nullptr, bo, d_out, nullptr, 0);
    layer4<512, 512, 512, 384, 784, 784, 16, false, true,  false, false>
        <<<NB, 1024, 0, stream>>>(actP, D3p, nullptr, nullptr, bo, d_out, nullptr, 512);

    reduce_abs<<<1, 256, 0, stream>>>(partials, (float*)d_out + (size_t)B_ROWS * 784);
}